// Round 9
// baseline (465.962 us; speedup 1.0000x reference)
//
#include <hip/hip_runtime.h>

// EncoderBlock on MI355X (gfx950). B=2,S=2048,D=1024,H=16,Dh=64.
// Round 9: attention computes S^T = K*Q^T (swapped MFMA operands) so the
// softmax lane owns 4 consecutive keys of one q-row -> packed b64 P-writes,
// float4 mask reads, scalar lsum. FFN2 = BN64 tile + split-K x2 (1024 blocks).

#define DEV __device__ __forceinline__

typedef unsigned short u16;
typedef __attribute__((ext_vector_type(8))) short bfrag;    // 8 bf16 payload
typedef __attribute__((ext_vector_type(8))) __bf16 bf16x8;  // MFMA operand type
typedef __attribute__((ext_vector_type(4))) float facc;     // MFMA C/D frag

DEV float bf2f(u16 u) {
  unsigned int x = ((unsigned int)u) << 16;
  return __builtin_bit_cast(float, x);
}
DEV u16 f2bf(float f) {
  unsigned int x = __builtin_bit_cast(unsigned int, f);
  x += 0x7fffu + ((x >> 16) & 1u);  // RNE
  return (u16)(x >> 16);
}
DEV unsigned int pkbf(float a, float b) {  // low=bf16(a), high=bf16(b)
  const unsigned int ua = (__builtin_bit_cast(unsigned int, a) + 0x8000u) >> 16;
  const unsigned int ub = (__builtin_bit_cast(unsigned int, b) + 0x8000u) & 0xffff0000u;
  return ua | ub;
}

DEV void gl2lds16(const u16* g, u16* l) {
  // async global->LDS DMA, 16B/lane; LDS dest = wave-uniform base + lane*16
  auto gp = (const __attribute__((address_space(1))) unsigned int*)(g);
  auto lp = (__attribute__((address_space(3))) unsigned int*)(l);
  __builtin_amdgcn_global_load_lds(gp, lp, 16, 0, 0);
}

DEV facc mfma16(bfrag a, bfrag b, facc c) {
  return __builtin_amdgcn_mfma_f32_16x16x32_bf16(
      __builtin_bit_cast(bf16x8, a), __builtin_bit_cast(bf16x8, b), c, 0, 0, 0);
}

// ---------------------------------------------------------------------------
// Merged prep: qkv transpose (jobs 0..3071), W1T (3072..7167),
// W2T (7168..11263), x cast (11264..15359). All fp32 -> bf16.
// ---------------------------------------------------------------------------
__global__ __launch_bounds__(256) void prep_kernel(
    const float* __restrict__ Wq, const float* __restrict__ Wk,
    const float* __restrict__ Wv, u16* __restrict__ WqkvT,
    const float* __restrict__ W1, u16* __restrict__ W1T,
    const float* __restrict__ W2, u16* __restrict__ W2T,
    const float* __restrict__ x, u16* __restrict__ xb) {
  __shared__ float tile[32][33];
  const int job = blockIdx.x;
  const int tr = threadIdx.x >> 5, tc = threadIdx.x & 31;

  if (job >= 11264) {  // cast x
    const int i = (job - 11264) * 1024 + threadIdx.x * 4;
    const float4 v = *(const float4*)(x + i);
    ushort4 o;
    o.x = f2bf(v.x); o.y = f2bf(v.y); o.z = f2bf(v.z); o.w = f2bf(v.w);
    *(ushort4*)(xb + i) = o;
    return;
  }

  const float* in;
  u16* out;
  int C, R, c0, r0;
  if (job < 3072) {  // qkv: [H][1024][64] -> rows which*1024+h*64+e, cols d
    const int z = job >> 6, rem = job & 63;
    const int which = z >> 4, h = z & 15;
    in = ((which == 0) ? Wq : (which == 1) ? Wk : Wv) + (size_t)h * 1024 * 64;
    out = WqkvT + ((size_t)which * 1024 + h * 64) * 1024;
    C = 64; R = 1024;
    c0 = (rem & 1) * 32; r0 = (rem >> 1) * 32;
  } else if (job < 7168) {  // W1 [1024][4096] -> W1T [4096][1024]
    const int rem = job - 3072;
    in = W1; out = W1T; C = 4096; R = 1024;
    c0 = (rem & 127) * 32; r0 = (rem >> 7) * 32;
  } else {  // W2 [4096][1024] -> W2T [1024][4096]
    const int rem = job - 7168;
    in = W2; out = W2T; C = 1024; R = 4096;
    c0 = (rem & 31) * 32; r0 = (rem >> 5) * 32;
  }
#pragma unroll
  for (int k = 0; k < 4; k++)
    tile[tr + 8 * k][tc] = in[(size_t)(r0 + tr + 8 * k) * C + c0 + tc];
  __syncthreads();
#pragma unroll
  for (int k = 0; k < 4; k++)
    out[(size_t)(c0 + tr + 8 * k) * R + r0 + tc] = f2bf(tile[tc][tr + 8 * k]);
}

// ---------------------------------------------------------------------------
// GEMM C[M][N] = A[M][K] * Bt[N][K]^T, 128xBN tile (BN=BNJ*32), BK=32,
// single-buffer m97 structure. GRID: blockIdx.x = M-tile (XCD L2 A-reuse),
// blockIdx.y = N-tile, blockIdx.z = K-split.
// MODE 0: QKV scatter +bias -> bf16 (V transposed [bh][e][s], packed stores).
// MODE 1: +bias, ReLU -> bf16.
// MODE 3: split-K partial -> bf16 partial buffer z (out0 + z*M*N).
// ---------------------------------------------------------------------------
template <int MODE, int BNJ>
__global__ __launch_bounds__(256) void gemm_bt(
    const u16* __restrict__ A, int lda, const u16* __restrict__ Bt, int ldb,
    int M, int N, int K,
    const float* __restrict__ bias0, const float* __restrict__ bias1,
    const float* __restrict__ bias2,
    void* __restrict__ out0, void* __restrict__ out1, void* __restrict__ out2) {
  constexpr int BN = BNJ * 32;
  __shared__ __align__(16) u16 As[4 * 128 * 8];
  __shared__ __align__(16) u16 Bs[4 * BN * 8];
  const int tid = threadIdx.x;
  const int lane = tid & 63;
  const int wave = tid >> 6;
  const int laneM = lane & 15, quad = lane >> 4;
  const int m0 = blockIdx.x * 128, n0 = blockIdx.y * BN;  // swizzled
  const int wm = wave & 1, wn = wave >> 1;

  if (MODE == 3) {  // split-K: shift K-origin
    A += (size_t)blockIdx.z * K;
    Bt += (size_t)blockIdx.z * K;
  }

  facc acc[4][BNJ] = {};

  for (int k0 = 0; k0 < K; k0 += 32) {
    __syncthreads();  // previous tile's readers done
#pragma unroll
    for (int t = 0; t < 2; t++) {
      const int c0 = t * 256 + wave * 64;  // wave-uniform chunk base
      const int kc = c0 >> 7, r0 = c0 & 127;
      gl2lds16(A + (size_t)(m0 + r0 + lane) * lda + (k0 + kc * 8),
               As + (size_t)c0 * 8);
    }
#pragma unroll
    for (int t = 0; t < BN / 64; t++) {
      const int c0 = t * 256 + wave * 64;
      const int kc = c0 / BN, r0 = c0 % BN;
      gl2lds16(Bt + (size_t)(n0 + r0 + lane) * ldb + (k0 + kc * 8),
               Bs + (size_t)c0 * 8);
    }
    __syncthreads();  // staging visible

    bfrag af[4], bfv[BNJ];
#pragma unroll
    for (int i = 0; i < 4; i++)
      af[i] = *(const bfrag*)(As + (quad * 128 + wm * 64 + i * 16 + laneM) * 8);
#pragma unroll
    for (int j = 0; j < BNJ; j++)
      bfv[j] = *(const bfrag*)(Bs + (quad * BN + wn * (BNJ * 16) + j * 16 + laneM) * 8);
#pragma unroll
    for (int i = 0; i < 4; i++)
#pragma unroll
      for (int j = 0; j < BNJ; j++)
        acc[i][j] = mfma16(af[i], bfv[j], acc[i][j]);
  }

  // epilogue: C/D layout col=lane&15, row=quad*4+v
#pragma unroll
  for (int i = 0; i < 4; i++) {
#pragma unroll
    for (int j = 0; j < BNJ; j++) {
      const int col = n0 + wn * (BNJ * 16) + j * 16 + laneM;
      const int row0 = m0 + wm * 64 + i * 16 + quad * 4;
      if (MODE == 0) {
        const int which = col >> 10, c = col & 1023;
        const float* bp = (which == 0) ? bias0 : (which == 1) ? bias1 : bias2;
        u16* op = (u16*)((which == 0) ? out0 : (which == 1) ? out1 : out2);
        const float bb = bp[c];
        const int b = row0 >> 11, s0 = row0 & 2047;
        const int h = c >> 6, e = c & 63;
        if (which == 2) {  // V^T [bh][e][s]: 4 consecutive s -> one 8B store
          ushort4 pk;
          pk.x = f2bf(acc[i][j][0] + bb);
          pk.y = f2bf(acc[i][j][1] + bb);
          pk.z = f2bf(acc[i][j][2] + bb);
          pk.w = f2bf(acc[i][j][3] + bb);
          *(ushort4*)(op + ((size_t)((b * 16 + h) * 64 + e)) * 2048 + s0) = pk;
        } else {
#pragma unroll
          for (int v = 0; v < 4; v++)
            op[((size_t)(b * 16 + h) * 2048 + s0 + v) * 64 + e] =
                f2bf(acc[i][j][v] + bb);
        }
      } else if (MODE == 1) {
        const float bb = bias0[col];
#pragma unroll
        for (int v = 0; v < 4; v++)
          ((u16*)out0)[(size_t)(row0 + v) * N + col] =
              f2bf(fmaxf(acc[i][j][v] + bb, 0.0f));
      } else {  // MODE 3: bf16 partial z
        u16* op = (u16*)out0 + (size_t)blockIdx.z * M * N;
#pragma unroll
        for (int v = 0; v < 4; v++)
          op[(size_t)(row0 + v) * N + col] = f2bf(acc[i][j][v]);
      }
    }
  }
}

// ---------------------------------------------------------------------------
// Flash attention, split-S, S^T variant: S^T = K*Q^T so C/D gives each lane
// 4 consecutive keys (rows) for one q-row (col=laneM). Softmax: fixed-max
// p = 2^(qk*0.125*log2e + maskbias); packed b64 P-writes; scalar lsum.
// GRID: x = bh (XCD K/V L2 locality), y = Q-tile, z = S-half.
// Q,K bf16 [bh][s][64]; V bf16 TRANSPOSED [bh][e][s].
// ---------------------------------------------------------------------------
__global__ __launch_bounds__(256) void attn_kernel(
    const u16* __restrict__ Qb, const u16* __restrict__ Kb,
    const u16* __restrict__ VTg, const int* __restrict__ mask,
    u16* __restrict__ Opart, float* __restrict__ lbuf) {
  __shared__ __align__(16) u16 KS[8 * 64 * 8];  // 8 KB: Q stage, then K tiles
  __shared__ __align__(16) u16 VS[8 * 64 * 8];  // 8 KB: V^T chunks kc*64+e
  __shared__ __align__(16) u16 PS[64 * 72];     // P [qrow][key], pitch 72
  __shared__ float MB[1024];                    // additive mask bias (half)
  const int tid = threadIdx.x;
  const int lane = tid & 63;
  const int wave = tid >> 6;
  const int laneM = lane & 15, quad = lane >> 4;
  const int bh = blockIdx.x, b = bh >> 4, h = bh & 15;  // swizzled
  const int q0 = blockIdx.y * 64;
  const int z = blockIdx.z;
  const int sbase = z * 1024;
  const u16* Qh = Qb + (size_t)bh * 2048 * 64;
  const u16* Kh = Kb + (size_t)bh * 2048 * 64 + (size_t)sbase * 64;
  const u16* Vh = VTg + (size_t)bh * 64 * 2048 + sbase;
  const float SC = 0.125f * 1.4426950408889634f;  // Dh^-0.5 * log2(e)

  // mask -> additive bias table for this half (once per block)
#pragma unroll
  for (int t = 0; t < 4; t++) {
    const int i = t * 256 + tid;
    MB[i] = mask[b * 2048 + sbase + i] ? 0.0f : -1e30f;
  }

  // stage Q tile (64x64) into KS as chunks c = kc*64 + r
#pragma unroll
  for (int t = 0; t < 2; t++) {
    const int c0 = t * 256 + wave * 64;
    gl2lds16(Qh + (size_t)(q0 + lane) * 64 + (c0 >> 6) * 8, KS + (size_t)c0 * 8);
  }
  __syncthreads();
  bfrag qf[2];  // Q[row=wave*16+laneM][k-half hf] -- B-operand for S^T
#pragma unroll
  for (int hf = 0; hf < 2; hf++)
    qf[hf] = *(const bfrag*)(KS + ((hf * 4 + quad) * 64 + wave * 16 + laneM) * 8);

  float lsum = 0.0f;  // partial sum for q-row (wave*16 + laneM)
  facc oacc[4] = {};

  for (int t0 = 0; t0 < 1024; t0 += 64) {
    __syncthreads();  // all waves done reading KS/VS (qf on iter 0)
#pragma unroll
    for (int t = 0; t < 2; t++) {
      const int c0 = t * 256 + wave * 64;
      gl2lds16(Kh + (size_t)(t0 + lane) * 64 + (c0 >> 6) * 8, KS + (size_t)c0 * 8);
    }
#pragma unroll
    for (int t = 0; t < 2; t++) {
      const int c0 = t * 256 + wave * 64;
      gl2lds16(Vh + (size_t)lane * 2048 + t0 + (c0 >> 6) * 8, VS + (size_t)c0 * 8);
    }
    __syncthreads();

    // S^T = K Q^T: A=K-frag (m=key), B=Q-frag (n=qrow).
    // C/D: col=laneM=qrow-local, row=quad*4+v=key-local (tile j8).
    facc sacc[4] = {};
#pragma unroll
    for (int j8 = 0; j8 < 4; j8++)
#pragma unroll
      for (int hf = 0; hf < 2; hf++) {
        bfrag kf = *(const bfrag*)(KS + ((hf * 4 + quad) * 64 + j8 * 16 + laneM) * 8);
        sacc[j8] = mfma16(kf, qf[hf], sacc[j8]);
      }

    // softmax: lane owns keys j8*16+quad*4+0..3 of q-row wave*16+laneM
#pragma unroll
    for (int j8 = 0; j8 < 4; j8++) {
      const float4 mb = *(const float4*)(MB + t0 + j8 * 16 + quad * 4);
      const float p0 = exp2f(fmaf(sacc[j8][0], SC, mb.x));
      const float p1 = exp2f(fmaf(sacc[j8][1], SC, mb.y));
      const float p2 = exp2f(fmaf(sacc[j8][2], SC, mb.z));
      const float p3 = exp2f(fmaf(sacc[j8][3], SC, mb.w));
      lsum += (p0 + p1) + (p2 + p3);
      uint2 w;
      w.x = pkbf(p0, p1);
      w.y = pkbf(p2, p3);
      *(uint2*)(PS + (wave * 16 + laneM) * 72 + j8 * 16 + quad * 4) = w;
    }

    // O += P @ V  (PS rows wave-private; VS chunk = kc*64 + e)
#pragma unroll
    for (int kc4 = 0; kc4 < 2; kc4++) {
      bfrag pf = *(const bfrag*)(PS + (wave * 16 + laneM) * 72 + kc4 * 32 + quad * 8);
#pragma unroll
      for (int je = 0; je < 4; je++) {
        bfrag vf = *(const bfrag*)(VS + ((kc4 * 4 + quad) * 64 + je * 16 + laneM) * 8);
        oacc[je] = mfma16(pf, vf, oacc[je]);
      }
    }
  }

  // reduce lsum across the 4 quads (same laneM): lanes laneM+16k hold q-row
  // wave*16+laneM. Then redistribute for O rows (quad*4+v).
  float l = lsum;
  l += __shfl_xor(l, 16, 64);
  l += __shfl_xor(l, 32, 64);
  const int sq = q0 + wave * 16 + laneM;
  if (quad == 0) lbuf[((size_t)(z * 32 + bh)) * 2048 + sq] = l;
#pragma unroll
  for (int v = 0; v < 4; v++) {
    const float lv = __shfl(l, quad * 4 + v, 16);  // l of q-row quad*4+v
    const int s = q0 + wave * 16 + quad * 4 + v;
    u16* dst = Opart + (size_t)z * 4096 * 1024 +
               ((size_t)(b * 2048 + s)) * 1024 + h * 64;
    (void)lv;  // partials stay unnormalized; lbuf carries l
#pragma unroll
    for (int je = 0; je < 4; je++)
      dst[je * 16 + laneM] = f2bf(oacc[je][v]);
  }
}

// ---------------------------------------------------------------------------
// x1 = x + LN((O0+O1)/(l0+l1)); fused attention combine + LayerNorm.
// O partials bf16. Writes fp32 + bf16 copies.
// ---------------------------------------------------------------------------
__global__ __launch_bounds__(256) void ln_attn(
    const float* __restrict__ base, const u16* __restrict__ Opart,
    const float* __restrict__ lbuf,
    const float* __restrict__ alpha, const float* __restrict__ beta,
    float* __restrict__ outf, u16* __restrict__ outb) {
  __shared__ float red[4];
  const int row = blockIdx.x;           // token = b*2048 + s
  const int t = threadIdx.x;
  const int b = row >> 11, s = row & 2047;
  const int h = t >> 4;                 // head of columns t*4..t*4+3
  const size_t off = (size_t)row * 1024 + t * 4;
  const size_t zstride = (size_t)4096 * 1024;

  const float l0 = lbuf[((size_t)(b * 16 + h)) * 2048 + s];
  const float l1 = lbuf[((size_t)(32 + b * 16 + h)) * 2048 + s];
  const float inv = 1.0f / (l0 + l1);

  const ushort4 o0 = *(const ushort4*)(Opart + off);
  const ushort4 o1 = *(const ushort4*)(Opart + zstride + off);
  float4 yv;
  yv.x = (bf2f(o0.x) + bf2f(o1.x)) * inv;
  yv.y = (bf2f(o0.y) + bf2f(o1.y)) * inv;
  yv.z = (bf2f(o0.z) + bf2f(o1.z)) * inv;
  yv.w = (bf2f(o0.w) + bf2f(o1.w)) * inv;

  float sm = yv.x + yv.y + yv.z + yv.w;
#pragma unroll
  for (int o = 1; o < 64; o <<= 1) sm += __shfl_xor(sm, o, 64);
  if ((t & 63) == 0) red[t >> 6] = sm;
  __syncthreads();
  const float mean = (red[0] + red[1] + red[2] + red[3]) * (1.0f / 1024.0f);
  __syncthreads();

  const float d0 = yv.x - mean, d1 = yv.y - mean, d2 = yv.z - mean, d3 = yv.w - mean;
  float ss = d0 * d0 + d1 * d1 + d2 * d2 + d3 * d3;
#pragma unroll
  for (int o = 1; o < 64; o <<= 1) ss += __shfl_xor(ss, o, 64);
  if ((t & 63) == 0) red[t >> 6] = ss;
  __syncthreads();
  const float var = (red[0] + red[1] + red[2] + red[3]) * (1.0f / 1023.0f);
  const float rstd = 1.0f / (sqrtf(var) + 1e-6f);

  const float4 bv = *(const float4*)(base + off);
  const float4 av = *(const float4*)(alpha + (size_t)t * 4);
  const float4 ev = *(const float4*)(beta + (size_t)t * 4);

  float4 ov;
  ov.x = bv.x + av.x * d0 * rstd + ev.x;
  ov.y = bv.y + av.y * d1 * rstd + ev.y;
  ov.z = bv.z + av.z * d2 * rstd + ev.z;
  ov.w = bv.w + av.w * d3 * rstd + ev.w;
  *(float4*)(outf + off) = ov;
  ushort4 ob;
  ob.x = f2bf(ov.x); ob.y = f2bf(ov.y); ob.z = f2bf(ov.z); ob.w = f2bf(ov.w);
  *(ushort4*)(outb + off) = ob;
}

// Final LN: y = sum of 2 bf16 split-K partials + bias; out fp32.
__global__ __launch_bounds__(256) void ln_res2(
    const float* __restrict__ base, const u16* __restrict__ parts,
    const float* __restrict__ biasv,
    const float* __restrict__ alpha, const float* __restrict__ beta,
    float* __restrict__ outf) {
  __shared__ float red[4];
  const int row = blockIdx.x;
  const int t = threadIdx.x;
  const size_t off = (size_t)row * 1024 + t * 4;
  const size_t stride = (size_t)4096 * 1024;

  float4 yv = *(const float4*)(biasv + (size_t)t * 4);
#pragma unroll
  for (int zi = 0; zi < 2; zi++) {
    const ushort4 pz = *(const ushort4*)(parts + zi * stride + off);
    yv.x += bf2f(pz.x); yv.y += bf2f(pz.y);
    yv.z += bf2f(pz.z); yv.w += bf2f(pz.w);
  }

  float s = yv.x + yv.y + yv.z + yv.w;
#pragma unroll
  for (int o = 1; o < 64; o <<= 1) s += __shfl_xor(s, o, 64);
  if ((t & 63) == 0) red[t >> 6] = s;
  __syncthreads();
  const float mean = (red[0] + red[1] + red[2] + red[3]) * (1.0f / 1024.0f);
  __syncthreads();

  const float d0 = yv.x - mean, d1 = yv.y - mean, d2 = yv.z - mean, d3 = yv.w - mean;
  float ss = d0 * d0 + d1 * d1 + d2 * d2 + d3 * d3;
#pragma unroll
  for (int o = 1; o < 64; o <<= 1) ss += __shfl_xor(ss, o, 64);
  if ((t & 63) == 0) red[t >> 6] = ss;
  __syncthreads();
  const float var = (red[0] + red[1] + red[2] + red[3]) * (1.0f / 1023.0f);
  const float rstd = 1.0f / (sqrtf(var) + 1e-6f);

  const float4 bv = *(const float4*)(base + off);
  const float4 av = *(const float4*)(alpha + (size_t)t * 4);
  const float4 ev = *(const float4*)(beta + (size_t)t * 4);

  float4 ov;
  ov.x = bv.x + av.x * d0 * rstd + ev.x;
  ov.y = bv.y + av.y * d1 * rstd + ev.y;
  ov.z = bv.z + av.z * d2 * rstd + ev.z;
  ov.w = bv.w + av.w * d3 * rstd + ev.w;
  *(float4*)(outf + off) = ov;
}

// ---------------------------------------------------------------------------
extern "C" void kernel_launch(void* const* d_in, const int* in_sizes, int n_in,
                              void* d_out, int out_size, void* d_ws,
                              size_t ws_size, hipStream_t stream) {
  const float* x  = (const float*)d_in[0];
  const int* mask = (const int*)d_in[1];
  const float* Wq = (const float*)d_in[2];
  const float* bq = (const float*)d_in[3];
  const float* Wk = (const float*)d_in[4];
  const float* bk = (const float*)d_in[5];
  const float* Wv = (const float*)d_in[6];
  const float* bv = (const float*)d_in[7];
  const float* W1 = (const float*)d_in[8];
  const float* b1 = (const float*)d_in[9];
  const float* W2 = (const float*)d_in[10];
  const float* b2 = (const float*)d_in[11];
  const float* alpha1 = (const float*)d_in[12];
  const float* beta1  = (const float*)d_in[13];
  const float* alpha2 = (const float*)d_in[14];
  const float* beta2  = (const float*)d_in[15];
  float* out = (float*)d_out;

  // workspace carve-up (bytes), total ~135 MB
  char* p = (char*)d_ws;
  u16* xb      = (u16*)p;  p += (size_t)4096 * 1024 * 2;
  u16* WqkvT   = (u16*)p;  p += (size_t)3072 * 1024 * 2;
  u16* W1T     = (u16*)p;  p += (size_t)4096 * 1024 * 2;
  u16* W2T     = (u16*)p;  p += (size_t)1024 * 4096 * 2;
  u16* Qbuf    = (u16*)p;  p += (size_t)32 * 2048 * 64 * 2;
  u16* Kbuf    = (u16*)p;  p += (size_t)32 * 2048 * 64 * 2;
  u16* Vbuf    = (u16*)p;  p += (size_t)32 * 2048 * 64 * 2;  // V^T [bh][e][s]
  u16* attnp   = (u16*)p;  p += (size_t)2 * 4096 * 1024 * 2;  // bf16 O partials
  float* lbuf  = (float*)p; p += (size_t)2 * 32 * 2048 * 4;   // l partials
  float* x1f   = (float*)p; p += (size_t)4096 * 1024 * 4;
  u16* x1b     = (u16*)p;  p += (size_t)4096 * 1024 * 2;
  u16* hbuf    = (u16*)p;  p += (size_t)4096 * 4096 * 2;
  u16* ffnp    = (u16*)p;  p += (size_t)2 * 4096 * 1024 * 2;  // 2 bf16 partials

  // 1) merged prep: transposes + x cast
  prep_kernel<<<15360, 256, 0, stream>>>(Wq, Wk, Wv, WqkvT, W1, W1T, W2, W2T,
                                         x, xb);

  // 2) fused QKV projection (V written transposed); x = M-tile
  gemm_bt<0, 4><<<dim3(32, 24), 256, 0, stream>>>(
      xb, 1024, WqkvT, 1024, 4096, 3072, 1024, bq, bk, bv, Qbuf, Kbuf, Vbuf);

  // 3) flash attention, split-S x2 -> unnormalized partials; x = bh
  attn_kernel<<<dim3(32, 32, 2), 256, 0, stream>>>(Qbuf, Kbuf, Vbuf, mask,
                                                   attnp, lbuf);

  // 4) x1 = x + LN(combine(attn))   (fp32 + bf16 copies)
  ln_attn<<<4096, 256, 0, stream>>>(x, attnp, lbuf, alpha1, beta1, x1f, x1b);

  // 5) h = relu(x1 @ W1 + b1) -> bf16; x = M-tile
  gemm_bt<1, 4><<<dim3(32, 32), 256, 0, stream>>>(
      x1b, 1024, W1T, 1024, 4096, 4096, 1024, b1, nullptr, nullptr,
      hbuf, nullptr, nullptr);

  // 6) ffn partials: h @ W2 split-K x2, BN=64 -> bf16 partials; 1024 blocks
  gemm_bt<3, 2><<<dim3(32, 16, 2), 256, 0, stream>>>(
      hbuf, 4096, W2T, 4096, 4096, 1024, 2048, nullptr, nullptr, nullptr,
      ffnp, nullptr, nullptr);

  // 7) out = x1 + LN(p0+p1 + b2)
  ln_res2<<<4096, 256, 0, stream>>>(x1f, ffnp, b2, alpha2, beta2, out);
}